// Round 7
// baseline (862.596 us; speedup 1.0000x reference)
//
#include <hip/hip_runtime.h>
#include <hip/hip_bf16.h>
#include <cstdint>
#include <cstddef>

namespace {
constexpr int B = 512, S = 200, D = 256, H = 4, DH = 64, NI = 100000;
constexpr float EPS = 1e-3f;
constexpr float SCALE = 0.125f;  // 1/sqrt(DH)
}

typedef __attribute__((ext_vector_type(8))) short bf16x8;
typedef __attribute__((ext_vector_type(4))) float f32x4;

__device__ inline unsigned short f2b(float f) {
  union { float f; unsigned int u; } v; v.f = f;
  unsigned int r = v.u + 0x7FFFu + ((v.u >> 16) & 1u);
  return (unsigned short)(r >> 16);
}

__device__ inline float b2f(unsigned short u) {
  union { unsigned int i; float f; } x; x.i = (unsigned int)u << 16; return x.f;
}

__device__ inline bf16x8 pack8(float4 a, float4 b) {
  bf16x8 r;
  r[0] = (short)f2b(a.x); r[1] = (short)f2b(a.y); r[2] = (short)f2b(a.z); r[3] = (short)f2b(a.w);
  r[4] = (short)f2b(b.x); r[5] = (short)f2b(b.y); r[6] = (short)f2b(b.z); r[7] = (short)f2b(b.w);
  return r;
}

__device__ inline ushort4 pack4(float4 a) {
  ushort4 r;
  r.x = f2b(a.x); r.y = f2b(a.y); r.z = f2b(a.z); r.w = f2b(a.w);
  return r;
}

__device__ inline float4 unpack4(ushort4 u) {
  float4 r; r.x = b2f(u.x); r.y = b2f(u.y); r.z = b2f(u.z); r.w = b2f(u.w); return r;
}

__device__ inline unsigned cvtpk(float lo, float hi) {
  unsigned r;
  asm("v_cvt_pk_bf16_f32 %0, %1, %2" : "=v"(r) : "v"(lo), "v"(hi));
  return r;
}

__device__ inline void gload_lds16(const unsigned short* g, unsigned short* l) {
  __builtin_amdgcn_global_load_lds((const __attribute__((address_space(1))) void*)g,
                                   (__attribute__((address_space(3))) void*)l, 16, 0, 0);
}

// ------- hidden weights [K][N] fp32 -> WT bf16 [w][N][K], w = blk*4+{q,k,v,d}
__global__ void cvt_wt_k(const float* __restrict__ wq, const float* __restrict__ wk,
                         const float* __restrict__ wv, const float* __restrict__ wd,
                         unsigned short* __restrict__ dst) {
  const int t = blockIdx.x * 256 + threadIdx.x;  // 131072 total
  const int w = t >> 14, rem = t & 16383;
  const int k = rem >> 6, n4 = (rem & 63) * 4;
  const int blk = w >> 2, which = w & 3;
  const float* src = (which == 0 ? wq : which == 1 ? wk : which == 2 ? wv : wd) + blk * 65536;
  const float4 v = *(const float4*)(src + k * 256 + n4);
  unsigned short* d = dst + w * 65536;
  d[(n4 + 0) * 256 + k] = f2b(v.x);
  d[(n4 + 1) * 256 + k] = f2b(v.y);
  d[(n4 + 2) * 256 + k] = f2b(v.z);
  d[(n4 + 3) * 256 + k] = f2b(v.w);
}

// ---------------- embedding gather + positional add -> bf16 seq ------------
__global__ void embed_k(const int* __restrict__ ids, const float* __restrict__ ie,
                        const float* __restrict__ pe, unsigned short* __restrict__ seq_bf) {
  const int total = B * S * (D / 4);
  for (int i = blockIdx.x * blockDim.x + threadIdx.x; i < total; i += gridDim.x * blockDim.x) {
    const int bs = i >> 6;
    const int d4 = (i & 63) << 2;
    const int id = ids[bs];
    const int s = bs % S;
    float4 a = *(const float4*)(ie + (size_t)id * D + d4);
    const float4 p = *(const float4*)(pe + (size_t)s * D + d4);
    a.x += p.x; a.y += p.y; a.z += p.z; a.w += p.w;
    *(ushort4*)(seq_bf + (size_t)bs * D + d4) = pack4(a);
  }
}

// ---------------- wave-per-row LayerNorm, bf16 in -> bf16 out --------------
__global__ __launch_bounds__(256) void ln_bf_k(const unsigned short* __restrict__ in,
                                               size_t in_stride,
                                               const float* __restrict__ g, const float* __restrict__ b,
                                               unsigned short* __restrict__ outp, int nrows) {
  const int row = blockIdx.x * 4 + (threadIdx.x >> 6);
  if (row >= nrows) return;
  const int lane = threadIdx.x & 63;
  const float4 v = unpack4(*(const ushort4*)(in + (size_t)row * in_stride + (lane << 2)));
  float s = v.x + v.y + v.z + v.w;
  float ss = v.x * v.x + v.y * v.y + v.z * v.z + v.w * v.w;
#pragma unroll
  for (int off = 32; off; off >>= 1) {
    s += __shfl_xor(s, off);
    ss += __shfl_xor(ss, off);
  }
  const float mean = s * (1.f / D);
  const float rs = rsqrtf(ss * (1.f / D) - mean * mean + EPS);
  const float4 gv = *(const float4*)(g + (lane << 2));
  const float4 bv = *(const float4*)(b + (lane << 2));
  float4 o;
  o.x = (v.x - mean) * rs * gv.x + bv.x;
  o.y = (v.y - mean) * rs * gv.y + bv.y;
  o.z = (v.z - mean) * rs * gv.z + bv.z;
  o.w = (v.w - mean) * rs * gv.w + bv.w;
  *(ushort4*)(outp + (size_t)row * D + (lane << 2)) = pack4(o);
}

// ------- fused: x2 = x_bf + o_bf (bf16 out) ; t = ln2(x2) (bf16, in-place) -
__global__ __launch_bounds__(256) void ln2x2_k(const unsigned short* __restrict__ x_bf,
                                               const unsigned short* __restrict__ o_bf,
                                               const float* __restrict__ g2, const float* __restrict__ b2,
                                               unsigned short* __restrict__ x2b,
                                               unsigned short* __restrict__ t_bf, int nrows) {
  const int row = blockIdx.x * 4 + (threadIdx.x >> 6);
  if (row >= nrows) return;
  const int lane = threadIdx.x & 63;
  const float4 xv = unpack4(*(const ushort4*)(x_bf + (size_t)row * D + (lane << 2)));
  const float4 ov = unpack4(*(const ushort4*)(o_bf + (size_t)row * D + (lane << 2)));
  float4 x2;
  x2.x = xv.x + ov.x; x2.y = xv.y + ov.y; x2.z = xv.z + ov.z; x2.w = xv.w + ov.w;
  *(ushort4*)(x2b + (size_t)row * D + (lane << 2)) = pack4(x2);
  float s2 = x2.x + x2.y + x2.z + x2.w;
  float ss2 = x2.x * x2.x + x2.y * x2.y + x2.z * x2.z + x2.w * x2.w;
#pragma unroll
  for (int off = 32; off; off >>= 1) {
    s2 += __shfl_xor(s2, off);
    ss2 += __shfl_xor(ss2, off);
  }
  const float mean2 = s2 * (1.f / D);
  const float rs2 = rsqrtf(ss2 * (1.f / D) - mean2 * mean2 + EPS);
  const float4 g2v = *(const float4*)(g2 + (lane << 2));
  const float4 b2v = *(const float4*)(b2 + (lane << 2));
  float4 t;
  t.x = (x2.x - mean2) * rs2 * g2v.x + b2v.x;
  t.y = (x2.y - mean2) * rs2 * g2v.y + b2v.y;
  t.z = (x2.z - mean2) * rs2 * g2v.z + b2v.z;
  t.w = (x2.w - mean2) * rs2 * g2v.w + b2v.w;
  *(ushort4*)(t_bf + (size_t)row * D + (lane << 2)) = pack4(t);
}

// -------- full-N hidden GEMM: C[M,256] = A[M,256] @ Wt[256,256]^T (+bias) --
// Tile 128x256, 8 waves, BK=64. osc: output scale (SCALE for Q GEMM).
// UPD=1: seq_bf = bf16((relu(y) + x2b) * mask).
template <int RELU, int UPD>
__global__ __launch_bounds__(512) void bgemm2_k(const unsigned short* __restrict__ A,
                                                const unsigned short* __restrict__ Wt,
                                                const float* __restrict__ bias,
                                                unsigned short* __restrict__ Cbf,
                                                const unsigned short* __restrict__ x2b,
                                                const int* __restrict__ ids, float osc) {
  __shared__ unsigned short As[128 * 64];
  __shared__ unsigned short Bs[256 * 64];
  const int tid = threadIdx.x, w = tid >> 6, lane = tid & 63;
  const int kb = lane >> 4, ln = lane & 15;
  const int m0 = blockIdx.x * 128;
  const int wm = w & 1, wn = w >> 1;

  f32x4 acc[4][4];
#pragma unroll
  for (int i = 0; i < 4; ++i)
#pragma unroll
    for (int j = 0; j < 4; ++j) acc[i][j] = (f32x4){0.f, 0.f, 0.f, 0.f};

  for (int ks = 0; ks < 4; ++ks) {
    const int ko = ks * 64;
#pragma unroll
    for (int r = 0; r < 2; ++r) {
      const int g = (w * 2 + r) * 64 + lane;
      const int row = g >> 3, gc = g & 7;
      gload_lds16(A + (size_t)(m0 + row) * 256 + ko + ((gc ^ (row & 7)) << 3),
                  As + (size_t)(w * 2 + r) * 512);
    }
#pragma unroll
    for (int r = 0; r < 4; ++r) {
      const int g = (w * 4 + r) * 64 + lane;
      const int row = g >> 3, gc = g & 7;
      gload_lds16(Wt + (size_t)row * 256 + ko + ((gc ^ (row & 7)) << 3),
                  Bs + (size_t)(w * 4 + r) * 512);
    }
    __syncthreads();
#pragma unroll
    for (int h = 0; h < 2; ++h) {
      bf16x8 af[4], bfr[4];
#pragma unroll
      for (int i = 0; i < 4; ++i) {
        const int ar = wm * 64 + i * 16 + ln;
        af[i] = *(const bf16x8*)(As + ar * 64 + (((h * 64 + kb * 16) ^ ((ar & 7) << 4)) >> 1));
        const int br = wn * 64 + i * 16 + ln;
        bfr[i] = *(const bf16x8*)(Bs + br * 64 + (((h * 64 + kb * 16) ^ ((br & 7) << 4)) >> 1));
      }
#pragma unroll
      for (int i = 0; i < 4; ++i)
#pragma unroll
        for (int j = 0; j < 4; ++j)
          acc[i][j] = __builtin_amdgcn_mfma_f32_16x16x32_bf16(af[i], bfr[j], acc[i][j], 0, 0, 0);
    }
    __syncthreads();
  }

  const int crow0 = m0 + wm * 64 + kb * 4;
  const int ccol0 = wn * 64 + ln;
  float mk[4][4];
  if (UPD) {
#pragma unroll
    for (int i = 0; i < 4; ++i)
#pragma unroll
      for (int r = 0; r < 4; ++r) mk[i][r] = (ids[crow0 + i * 16 + r] != NI) ? 1.f : 0.f;
  }
#pragma unroll
  for (int j = 0; j < 4; ++j) {
    const int col = ccol0 + j * 16;
    const float bj = bias[col];
#pragma unroll
    for (int i = 0; i < 4; ++i) {
#pragma unroll
      for (int r = 0; r < 4; ++r) {
        const int row = crow0 + i * 16 + r;
        float v = (acc[i][j][r] + bj) * osc;
        if (RELU) v = fmaxf(v, 0.f);
        if (UPD) v = (v + b2f(x2b[(size_t)row * 256 + col])) * mk[i][r];
        Cbf[(size_t)row * 256 + col] = f2b(v);
      }
    }
  }
}

// ------- logits GEMM: C[M,N] f32 = A(bf16) @ W(f32->bf16 reg-staged)^T ------
__global__ __launch_bounds__(256) void bgemm3_k(const unsigned short* __restrict__ A,
                                                const float* __restrict__ Wf,
                                                float* __restrict__ C, int M, int N) {
  __shared__ unsigned short As[128 * 64];
  __shared__ unsigned short Bs[128 * 64];
  const int tid = threadIdx.x, w = tid >> 6, lane = tid & 63;
  const int kb = lane >> 4, ln = lane & 15;
  const int m0 = blockIdx.x * 128;
  const int n0 = blockIdx.y * 128;
  const int wm = w & 1, wn = w >> 1;
  const int rl = lane >> 3;
  const int cb = (lane & 7) << 4;

  f32x4 acc[4][4];
#pragma unroll
  for (int i = 0; i < 4; ++i)
#pragma unroll
    for (int j = 0; j < 4; ++j) acc[i][j] = (f32x4){0.f, 0.f, 0.f, 0.f};

  for (int ks = 0; ks < 4; ++ks) {
    const int ko = ks * 64;
#pragma unroll
    for (int c = 0; c < 4; ++c) {
      const int arow = w * 32 + c * 8 + rl;
      const int sw = (arow & 7) << 4;
      const int cu = (cb ^ sw) >> 1;
      gload_lds16(A + (size_t)(m0 + arow) * 256 + ko + cu, As + (w * 32 + c * 8) * 64);
    }
    // B: reg-stage f32 -> bf16 into swizzled LDS slots
#pragma unroll
    for (int c = 0; c < 4; ++c) {
      const int g = c * 256 + tid;
      const int row = g >> 3, gcs = g & 7;
      int br = n0 + row; if (br > N - 1) br = N - 1;
      const float* src = Wf + (size_t)br * 256 + ko + gcs * 8;
      const float4 f0 = *(const float4*)src;
      const float4 f1 = *(const float4*)(src + 4);
      *(bf16x8*)(Bs + row * 64 + ((gcs ^ (row & 7)) << 3)) = pack8(f0, f1);
    }
    __syncthreads();
#pragma unroll
    for (int h = 0; h < 2; ++h) {
      bf16x8 af[4], bfr[4];
#pragma unroll
      for (int i = 0; i < 4; ++i) {
        const int ar = wm * 64 + i * 16 + ln;
        af[i] = *(const bf16x8*)(As + ar * 64 + (((h * 64 + kb * 16) ^ ((ar & 7) << 4)) >> 1));
        const int br = wn * 64 + i * 16 + ln;
        bfr[i] = *(const bf16x8*)(Bs + br * 64 + (((h * 64 + kb * 16) ^ ((br & 7) << 4)) >> 1));
      }
#pragma unroll
      for (int i = 0; i < 4; ++i)
#pragma unroll
        for (int j = 0; j < 4; ++j)
          acc[i][j] = __builtin_amdgcn_mfma_f32_16x16x32_bf16(af[i], bfr[j], acc[i][j], 0, 0, 0);
    }
    __syncthreads();
  }

  const int crow0 = m0 + wm * 64 + kb * 4;
  const int ccol0 = n0 + wn * 64 + ln;
#pragma unroll
  for (int j = 0; j < 4; ++j) {
    const int col = ccol0 + j * 16;
    if (col >= N) continue;
#pragma unroll
    for (int i = 0; i < 4; ++i) {
#pragma unroll
      for (int r = 0; r < 4; ++r) {
        const int row = crow0 + i * 16 + r;
        C[(size_t)row * N + col] = acc[i][j][r];
      }
    }
  }
}

// ------- V transpose: v_bf [M][256] -> vt [bh][kg=26][d=64][8] granules -----
// (content: vt granule (kg,d) = V^T[d][k=kg*8..+7]; keys 200..207 zeroed)
__global__ __launch_bounds__(256) void vT_k(const unsigned short* __restrict__ V,
                                            unsigned short* __restrict__ VT) {
  __shared__ unsigned short tile[64][72];
  const int bh = blockIdx.x >> 2;
  const int sc = blockIdx.x & 3;
  const int b = bh >> 2, h = bh & 3;
  const int k0 = sc * 64;
  const int tid = threadIdx.x;
  for (int g = tid; g < 512; g += 256) {
    const int kr = g >> 3, dq = g & 7;
    bf16x8 v = (bf16x8)0;
    const int key = k0 + kr;
    if (key < 200) v = *(const bf16x8*)(V + (size_t)(b * 200 + key) * 256 + h * 64 + dq * 8);
    *(bf16x8*)(&tile[kr][dq * 8]) = v;
  }
  __syncthreads();
  for (int g = tid; g < 512; g += 256) {
    const int d = g & 63, kgl = g >> 6;
    const int kg = (k0 >> 3) + kgl;
    if (kg >= 26) continue;
    bf16x8 o;
#pragma unroll
    for (int j = 0; j < 8; ++j) o[j] = tile[kgl * 8 + j][d];
    *(bf16x8*)(VT + (size_t)bh * 13312 + ((size_t)kg * 64 + d) * 8) = o;
  }
}

// ---------------- MFMA causal attention v3: swapped QK^T -------------------
// sc = S^T fragments (lane owns query q=ln); in-lane softmax; P normalized,
// cvt_pk-packed, bpermute-redistributed into PV A-fragments. No P LDS.
// LDS 53,248 B -> 3 blocks/CU. K and V^T staged via global_load_lds only.
__global__ __launch_bounds__(256, 3) void attn3_k(const unsigned short* __restrict__ Q,
                                                  const unsigned short* __restrict__ Kg,
                                                  const unsigned short* __restrict__ VT,
                                                  unsigned short* __restrict__ O) {
  __shared__ unsigned short Ks[13312];   // 26 sets x 512 ([t][h2] granules)
  __shared__ unsigned short Vs[13312];   // 26 sets x 512 ([kg][d] granules)
  const int b = blockIdx.x >> 2;
  const int h = blockIdx.x & 3;
  const int tid = threadIdx.x, w = tid >> 6, lane = tid & 63;
  const int kb = lane >> 4, ln = lane & 15;
  const size_t base = (size_t)b * S * D + h * DH;
  const unsigned short* vt = VT + (size_t)(b * 4 + h) * 13312;

  for (int s = w; s < 26; s += 4) {
    const int t = s >> 1, h2 = s & 1;
    int krow = t * 16 + ln; if (krow > S - 1) krow = S - 1;
    gload_lds16(Kg + base + (size_t)krow * D + h2 * 32 + kb * 8, Ks + s * 512);
    gload_lds16(vt + s * 512 + lane * 8, Vs + s * 512);
  }
  __syncthreads();

  for (int q0 = w * 16; q0 < S; q0 += 64) {
    int qr = q0 + ln; if (qr > S - 1) qr = S - 1;
    const unsigned short* qp = Q + base + (size_t)qr * D + kb * 8;
    const bf16x8 bq0 = *(const bf16x8*)(qp);
    const bf16x8 bq1 = *(const bf16x8*)(qp + 32);
    // ---- QK^T swapped: sc[t][r] = S[key = t*16+kb*4+r][q = q0+ln] ----
    f32x4 sc[13];
#pragma unroll
    for (int t = 0; t < 13; ++t) {
      f32x4 a = {0.f, 0.f, 0.f, 0.f};
      a = __builtin_amdgcn_mfma_f32_16x16x32_bf16(*(const bf16x8*)(Ks + (t * 2 + 0) * 512 + lane * 8), bq0, a, 0, 0, 0);
      a = __builtin_amdgcn_mfma_f32_16x16x32_bf16(*(const bf16x8*)(Ks + (t * 2 + 1) * 512 + lane * 8), bq1, a, 0, 0, 0);
      sc[t] = a;
    }
    // ---- in-lane softmax over keys for q = q0+ln (Q pre-scaled) ----
    const int q = q0 + ln;
    float m = -1e30f;
#pragma unroll
    for (int t = 0; t < 13; ++t) {
#pragma unroll
      for (int r = 0; r < 4; ++r) {
        const int key = t * 16 + kb * 4 + r;
        float s = sc[t][r];
        s = (key <= q) ? s : -1e30f;
        sc[t][r] = s;
        m = fmaxf(m, s);
      }
    }
    m = fmaxf(m, __shfl_xor(m, 16));
    m = fmaxf(m, __shfl_xor(m, 32));
    float sm = 0.f;
#pragma unroll
    for (int t = 0; t < 13; ++t) {
#pragma unroll
      for (int r = 0; r < 4; ++r) {
        const float e = __expf(sc[t][r] - m);
        sc[t][r] = e;
        sm += e;
      }
    }
    sm += __shfl_xor(sm, 16);
    sm += __shfl_xor(sm, 32);
    const float inv = 1.f / sm;
    // ---- pack P' = P*inv to bf16, bpermute into A-fragment granules ----
    int4 pg[7];
#pragma unroll
    for (int i = 0; i < 7; ++i) pg[i] = (int4){0, 0, 0, 0};
    const int s0 = ((kb & 1) << 5) + ln;
#pragma unroll
    for (int t = 0; t < 13; ++t) {
      const int lo = (int)cvtpk(sc[t][0] * inv, sc[t][1] * inv);
      const int hi = (int)cvtpk(sc[t][2] * inv, sc[t][3] * inv);
      const int b0 = __shfl(lo, s0);
      const int b1 = __shfl(hi, s0);
      const int b2 = __shfl(lo, s0 + 16);
      const int b3 = __shfl(hi, s0 + 16);
      if ((t & 1) == (kb >> 1)) pg[t >> 1] = (int4){b0, b1, b2, b3};
    }
    // ---- PV: O[q=kb*4+r][d=ct*16+ln], A = pg, B = Vs granules ----
#pragma unroll
    for (int ct = 0; ct < 4; ++ct) {
      f32x4 a = {0.f, 0.f, 0.f, 0.f};
#pragma unroll
      for (int kt = 0; kt < 6; ++kt) {
        const bf16x8 pa = *(const bf16x8*)&pg[kt];
        const bf16x8 vb = *(const bf16x8*)(Vs + ((kt * 4 + kb) * 64 + ct * 16 + ln) * 8);
        a = __builtin_amdgcn_mfma_f32_16x16x32_bf16(pa, vb, a, 0, 0, 0);
      }
      {
        const int kg6 = 24 + (kb & 1);
        const bf16x8 vb = *(const bf16x8*)(Vs + (kg6 * 64 + ct * 16 + ln) * 8);
        bf16x8 pa = (bf16x8)0;
        if (kb < 2) pa = *(const bf16x8*)&pg[6];
        a = __builtin_amdgcn_mfma_f32_16x16x32_bf16(pa, vb, a, 0, 0, 0);
      }
#pragma unroll
      for (int r = 0; r < 4; ++r) {
        const int qq = q0 + kb * 4 + r;
        if (qq < S) O[base + (size_t)qq * D + ct * 16 + ln] = f2b(a[r]);
      }
    }
  }
}

// ---------------------------------------------------------------------------
extern "C" void kernel_launch(void* const* d_in, const int* in_sizes, int n_in,
                              void* d_out, int out_size, void* d_ws, size_t ws_size,
                              hipStream_t stream) {
  const int* ids        = (const int*)d_in[0];
  const float* item_emb = (const float*)d_in[1];
  const float* pos_emb  = (const float*)d_in[2];
  const float* ln1_g    = (const float*)d_in[3];
  const float* ln1_b    = (const float*)d_in[4];
  const float* wq       = (const float*)d_in[5];
  const float* bq       = (const float*)d_in[6];
  const float* wk       = (const float*)d_in[7];
  const float* bk       = (const float*)d_in[8];
  const float* wv       = (const float*)d_in[9];
  const float* bv       = (const float*)d_in[10];
  const float* ln2_g    = (const float*)d_in[11];
  const float* ln2_b    = (const float*)d_in[12];
  const float* wd       = (const float*)d_in[13];
  const float* bd       = (const float*)d_in[14];
  const float* seq_g    = (const float*)d_in[15];
  const float* seq_b    = (const float*)d_in[16];
  const float* w_out    = (const float*)d_in[17];
  float* out = (float*)d_out;

  // ---- workspace layout (bytes), end = 422,838,272 ----
  char* wsb = (char*)d_ws;
  unsigned short* seq_bf = (unsigned short*)(wsb + 0);
  unsigned short* x_bf   = (unsigned short*)(wsb + 52428800);
  unsigned short* q_bf   = (unsigned short*)(wsb + 104857600);
  unsigned short* k_bf   = (unsigned short*)(wsb + 157286400);
  unsigned short* v_bf   = (unsigned short*)(wsb + 209715200);
  unsigned short* o_bf   = (unsigned short*)(wsb + 262144000);
  unsigned short* x2b    = (unsigned short*)(wsb + 314572800);
  unsigned short* vt     = (unsigned short*)(wsb + 367001600);  // 54,525,952 B
  unsigned short* wtb    = (unsigned short*)(wsb + 421527552);  // 1,048,576 B
  unsigned short* semb   = (unsigned short*)(wsb + 422576128);  // 262,144 B

  const int M = B * S;  // 102400
  const int ln_grid = (M + 3) / 4;

  cvt_wt_k<<<512, 256, 0, stream>>>(wq, wk, wv, wd, wtb);
  embed_k<<<2048, 256, 0, stream>>>(ids, item_emb, pos_emb, seq_bf);

  for (int blk = 0; blk < 2; ++blk) {
    const float* l1g = ln1_g + blk * D;
    const float* l1b = ln1_b + blk * D;
    const float* l2g = ln2_g + blk * D;
    const float* l2b = ln2_b + blk * D;
    const unsigned short* WT = wtb + (size_t)blk * 4 * 65536;  // order: q,k,v,d

    bgemm2_k<0, 0><<<800, 512, 0, stream>>>(seq_bf, WT + 1 * 65536, bk + blk * D, k_bf, nullptr, nullptr, 1.f);
    bgemm2_k<0, 0><<<800, 512, 0, stream>>>(seq_bf, WT + 2 * 65536, bv + blk * D, v_bf, nullptr, nullptr, 1.f);
    vT_k<<<B * H * 4, 256, 0, stream>>>(v_bf, vt);
    ln_bf_k<<<ln_grid, 256, 0, stream>>>(seq_bf, D, l1g, l1b, x_bf, M);
    bgemm2_k<0, 0><<<800, 512, 0, stream>>>(x_bf, WT + 0 * 65536, bq + blk * D, q_bf, nullptr, nullptr, SCALE);
    attn3_k<<<B * H, 256, 0, stream>>>(q_bf, k_bf, vt, o_bf);
    ln2x2_k<<<ln_grid, 256, 0, stream>>>(x_bf, o_bf, l2g, l2b, x2b, x_bf, M);
    bgemm2_k<1, 1><<<800, 512, 0, stream>>>(x_bf, WT + 3 * 65536, bd + blk * D, seq_bf, x2b, ids, 1.f);
  }

  ln_bf_k<<<(B + 3) / 4, 256, 0, stream>>>(seq_bf + (size_t)(S - 1) * D, (size_t)S * D,
                                           seq_g, seq_b, semb, B);
  bgemm3_k<<<dim3(4, 782), 256, 0, stream>>>(semb, w_out, out, B, NI);
}

// Round 8
// 775.930 us; speedup vs baseline: 1.1117x; 1.1117x over previous
//
#include <hip/hip_runtime.h>
#include <hip/hip_bf16.h>
#include <cstdint>
#include <cstddef>

namespace {
constexpr int B = 512, S = 200, D = 256, H = 4, DH = 64, NI = 100000;
constexpr float EPS = 1e-3f;
constexpr float SCALE = 0.125f;  // 1/sqrt(DH)
}

typedef __attribute__((ext_vector_type(8))) short bf16x8;
typedef __attribute__((ext_vector_type(4))) float f32x4;

__device__ inline unsigned short f2b(float f) {
  union { float f; unsigned int u; } v; v.f = f;
  unsigned int r = v.u + 0x7FFFu + ((v.u >> 16) & 1u);
  return (unsigned short)(r >> 16);
}

__device__ inline float b2f(unsigned short u) {
  union { unsigned int i; float f; } x; x.i = (unsigned int)u << 16; return x.f;
}

__device__ inline bf16x8 pack8(float4 a, float4 b) {
  bf16x8 r;
  r[0] = (short)f2b(a.x); r[1] = (short)f2b(a.y); r[2] = (short)f2b(a.z); r[3] = (short)f2b(a.w);
  r[4] = (short)f2b(b.x); r[5] = (short)f2b(b.y); r[6] = (short)f2b(b.z); r[7] = (short)f2b(b.w);
  return r;
}

__device__ inline ushort4 pack4(float4 a) {
  ushort4 r;
  r.x = f2b(a.x); r.y = f2b(a.y); r.z = f2b(a.z); r.w = f2b(a.w);
  return r;
}

__device__ inline float4 unpack4(ushort4 u) {
  float4 r; r.x = b2f(u.x); r.y = b2f(u.y); r.z = b2f(u.z); r.w = b2f(u.w); return r;
}

__device__ inline void gload_lds16(const unsigned short* g, unsigned short* l) {
  __builtin_amdgcn_global_load_lds((const __attribute__((address_space(1))) void*)g,
                                   (__attribute__((address_space(3))) void*)l, 16, 0, 0);
}

// ------- hidden weights [K][N] fp32 -> WT bf16 [w][N][K], w = blk*4+{q,k,v,d}
__global__ void cvt_wt_k(const float* __restrict__ wq, const float* __restrict__ wk,
                         const float* __restrict__ wv, const float* __restrict__ wd,
                         unsigned short* __restrict__ dst) {
  const int t = blockIdx.x * 256 + threadIdx.x;  // 131072 total
  const int w = t >> 14, rem = t & 16383;
  const int k = rem >> 6, n4 = (rem & 63) * 4;
  const int blk = w >> 2, which = w & 3;
  const float* src = (which == 0 ? wq : which == 1 ? wk : which == 2 ? wv : wd) + blk * 65536;
  const float4 v = *(const float4*)(src + k * 256 + n4);
  unsigned short* d = dst + w * 65536;
  d[(n4 + 0) * 256 + k] = f2b(v.x);
  d[(n4 + 1) * 256 + k] = f2b(v.y);
  d[(n4 + 2) * 256 + k] = f2b(v.z);
  d[(n4 + 3) * 256 + k] = f2b(v.w);
}

// ------- embed + pos, fused with ln1 of layer 0: wave-per-row --------------
// writes seq_bf = bf16(emb+pos) and x_bf = bf16(ln1(emb+pos))
__global__ __launch_bounds__(256) void embed_ln_k(const int* __restrict__ ids,
                                                  const float* __restrict__ ie,
                                                  const float* __restrict__ pe,
                                                  const float* __restrict__ g1,
                                                  const float* __restrict__ b1,
                                                  unsigned short* __restrict__ seq_bf,
                                                  unsigned short* __restrict__ x_bf) {
  const int row = blockIdx.x * 4 + (threadIdx.x >> 6);
  const int lane = threadIdx.x & 63;
  const int id = ids[row];
  const int s = row % S;
  float4 v = *(const float4*)(ie + (size_t)id * D + (lane << 2));
  const float4 p = *(const float4*)(pe + (size_t)s * D + (lane << 2));
  v.x += p.x; v.y += p.y; v.z += p.z; v.w += p.w;
  *(ushort4*)(seq_bf + (size_t)row * D + (lane << 2)) = pack4(v);
  // stats on the bf16-rounded values (match previous ln_bf numerics)
  const float4 vb = unpack4(pack4(v));
  float su = vb.x + vb.y + vb.z + vb.w;
  float ss = vb.x * vb.x + vb.y * vb.y + vb.z * vb.z + vb.w * vb.w;
#pragma unroll
  for (int off = 32; off; off >>= 1) {
    su += __shfl_xor(su, off);
    ss += __shfl_xor(ss, off);
  }
  const float mean = su * (1.f / D);
  const float rs = rsqrtf(ss * (1.f / D) - mean * mean + EPS);
  const float4 gv = *(const float4*)(g1 + (lane << 2));
  const float4 bv = *(const float4*)(b1 + (lane << 2));
  float4 o;
  o.x = (vb.x - mean) * rs * gv.x + bv.x;
  o.y = (vb.y - mean) * rs * gv.y + bv.y;
  o.z = (vb.z - mean) * rs * gv.z + bv.z;
  o.w = (vb.w - mean) * rs * gv.w + bv.w;
  *(ushort4*)(x_bf + (size_t)row * D + (lane << 2)) = pack4(o);
}

// ---------------- wave-per-row LayerNorm, bf16 in -> bf16 out (semb) -------
__global__ __launch_bounds__(256) void ln_bf_k(const unsigned short* __restrict__ in,
                                               size_t in_stride,
                                               const float* __restrict__ g, const float* __restrict__ b,
                                               unsigned short* __restrict__ outp, int nrows) {
  const int row = blockIdx.x * 4 + (threadIdx.x >> 6);
  if (row >= nrows) return;
  const int lane = threadIdx.x & 63;
  const float4 v = unpack4(*(const ushort4*)(in + (size_t)row * in_stride + (lane << 2)));
  float s = v.x + v.y + v.z + v.w;
  float ss = v.x * v.x + v.y * v.y + v.z * v.z + v.w * v.w;
#pragma unroll
  for (int off = 32; off; off >>= 1) {
    s += __shfl_xor(s, off);
    ss += __shfl_xor(ss, off);
  }
  const float mean = s * (1.f / D);
  const float rs = rsqrtf(ss * (1.f / D) - mean * mean + EPS);
  const float4 gv = *(const float4*)(g + (lane << 2));
  const float4 bv = *(const float4*)(b + (lane << 2));
  float4 o;
  o.x = (v.x - mean) * rs * gv.x + bv.x;
  o.y = (v.y - mean) * rs * gv.y + bv.y;
  o.z = (v.z - mean) * rs * gv.z + bv.z;
  o.w = (v.w - mean) * rs * gv.w + bv.w;
  *(ushort4*)(outp + (size_t)row * D + (lane << 2)) = pack4(o);
}

// ------- fused: x2 = x_bf + o_bf (bf16 out) ; t = ln2(x2) ------------------
__global__ __launch_bounds__(256) void ln2x2_k(const unsigned short* __restrict__ x_bf,
                                               const unsigned short* __restrict__ o_bf,
                                               const float* __restrict__ g2, const float* __restrict__ b2,
                                               unsigned short* __restrict__ x2b,
                                               unsigned short* __restrict__ t_bf, int nrows) {
  const int row = blockIdx.x * 4 + (threadIdx.x >> 6);
  if (row >= nrows) return;
  const int lane = threadIdx.x & 63;
  const float4 xv = unpack4(*(const ushort4*)(x_bf + (size_t)row * D + (lane << 2)));
  const float4 ov = unpack4(*(const ushort4*)(o_bf + (size_t)row * D + (lane << 2)));
  float4 x2;
  x2.x = xv.x + ov.x; x2.y = xv.y + ov.y; x2.z = xv.z + ov.z; x2.w = xv.w + ov.w;
  *(ushort4*)(x2b + (size_t)row * D + (lane << 2)) = pack4(x2);
  float s2 = x2.x + x2.y + x2.z + x2.w;
  float ss2 = x2.x * x2.x + x2.y * x2.y + x2.z * x2.z + x2.w * x2.w;
#pragma unroll
  for (int off = 32; off; off >>= 1) {
    s2 += __shfl_xor(s2, off);
    ss2 += __shfl_xor(ss2, off);
  }
  const float mean2 = s2 * (1.f / D);
  const float rs2 = rsqrtf(ss2 * (1.f / D) - mean2 * mean2 + EPS);
  const float4 g2v = *(const float4*)(g2 + (lane << 2));
  const float4 b2v = *(const float4*)(b2 + (lane << 2));
  float4 t;
  t.x = (x2.x - mean2) * rs2 * g2v.x + b2v.x;
  t.y = (x2.y - mean2) * rs2 * g2v.y + b2v.y;
  t.z = (x2.z - mean2) * rs2 * g2v.z + b2v.z;
  t.w = (x2.w - mean2) * rs2 * g2v.w + b2v.w;
  *(ushort4*)(t_bf + (size_t)row * D + (lane << 2)) = pack4(t);
}

// -------- full-N hidden GEMM: C[M,256] = A[M,256] @ Wt[256,256]^T (+bias) --
// Tile 128x256, 8 waves, BK=64. osc: output scale (SCALE for Q GEMM).
// UPD=1: seq = bf16((relu(y) + x2b) * mask).
// LN1=1: additionally x1 = bf16(ln1_next(seq)) via cross-wave LDS reduction
//        (tile holds full rows, so row stats are block-local).
template <int RELU, int UPD, int LN1>
__global__ __launch_bounds__(512) void bgemm2_k(const unsigned short* __restrict__ A,
                                                const unsigned short* __restrict__ Wt,
                                                const float* __restrict__ bias,
                                                unsigned short* __restrict__ Cbf,
                                                const unsigned short* __restrict__ x2b,
                                                const int* __restrict__ ids, float osc,
                                                const float* __restrict__ g1,
                                                const float* __restrict__ b1,
                                                unsigned short* __restrict__ x1) {
  __shared__ unsigned short As[128 * 64];
  __shared__ unsigned short Bs[256 * 64];
  const int tid = threadIdx.x, w = tid >> 6, lane = tid & 63;
  const int kb = lane >> 4, ln = lane & 15;
  const int m0 = blockIdx.x * 128;
  const int wm = w & 1, wn = w >> 1;

  f32x4 acc[4][4];
#pragma unroll
  for (int i = 0; i < 4; ++i)
#pragma unroll
    for (int j = 0; j < 4; ++j) acc[i][j] = (f32x4){0.f, 0.f, 0.f, 0.f};

  for (int ks = 0; ks < 4; ++ks) {
    const int ko = ks * 64;
#pragma unroll
    for (int r = 0; r < 2; ++r) {
      const int g = (w * 2 + r) * 64 + lane;
      const int row = g >> 3, gc = g & 7;
      gload_lds16(A + (size_t)(m0 + row) * 256 + ko + ((gc ^ (row & 7)) << 3),
                  As + (size_t)(w * 2 + r) * 512);
    }
#pragma unroll
    for (int r = 0; r < 4; ++r) {
      const int g = (w * 4 + r) * 64 + lane;
      const int row = g >> 3, gc = g & 7;
      gload_lds16(Wt + (size_t)row * 256 + ko + ((gc ^ (row & 7)) << 3),
                  Bs + (size_t)(w * 4 + r) * 512);
    }
    __syncthreads();
#pragma unroll
    for (int h = 0; h < 2; ++h) {
      bf16x8 af[4], bfr[4];
#pragma unroll
      for (int i = 0; i < 4; ++i) {
        const int ar = wm * 64 + i * 16 + ln;
        af[i] = *(const bf16x8*)(As + ar * 64 + (((h * 64 + kb * 16) ^ ((ar & 7) << 4)) >> 1));
        const int br = wn * 64 + i * 16 + ln;
        bfr[i] = *(const bf16x8*)(Bs + br * 64 + (((h * 64 + kb * 16) ^ ((br & 7) << 4)) >> 1));
      }
#pragma unroll
      for (int i = 0; i < 4; ++i)
#pragma unroll
        for (int j = 0; j < 4; ++j)
          acc[i][j] = __builtin_amdgcn_mfma_f32_16x16x32_bf16(af[i], bfr[j], acc[i][j], 0, 0, 0);
    }
    __syncthreads();
  }

  const int crow0 = m0 + wm * 64 + kb * 4;
  const int ccol0 = wn * 64 + ln;
  float mk[4][4];
  if (UPD) {
#pragma unroll
    for (int i = 0; i < 4; ++i)
#pragma unroll
      for (int r = 0; r < 4; ++r) mk[i][r] = (ids[crow0 + i * 16 + r] != NI) ? 1.f : 0.f;
  }
#pragma unroll
  for (int j = 0; j < 4; ++j) {
    const int col = ccol0 + j * 16;
    const float bj = bias[col];
#pragma unroll
    for (int i = 0; i < 4; ++i) {
#pragma unroll
      for (int r = 0; r < 4; ++r) {
        const int row = crow0 + i * 16 + r;
        float v = (acc[i][j][r] + bj) * osc;
        if (RELU) v = fmaxf(v, 0.f);
        if (UPD) v = (v + b2f(x2b[(size_t)row * 256 + col])) * mk[i][r];
        const unsigned short vb = f2b(v);
        Cbf[(size_t)row * 256 + col] = vb;
        if (LN1) acc[i][j][r] = b2f(vb);  // keep rounded value for LN stats
      }
    }
  }

  if (LN1) {
    // per-(i,r) row partial sums over this lane's 4 cols, reduce across ln
    float s_[4][4], ss_[4][4];
#pragma unroll
    for (int i = 0; i < 4; ++i)
#pragma unroll
      for (int r = 0; r < 4; ++r) {
        float s = 0.f, ss = 0.f;
#pragma unroll
        for (int j = 0; j < 4; ++j) { const float v = acc[i][j][r]; s += v; ss += v * v; }
#pragma unroll
        for (int off = 1; off < 16; off <<= 1) {
          s += __shfl_xor(s, off);
          ss += __shfl_xor(ss, off);
        }
        s_[i][r] = s; ss_[i][r] = ss;
      }
    float* red = (float*)As;  // 128 rows x 4 wn x 2 floats = 4 KB
    if (ln == 0) {
#pragma unroll
      for (int i = 0; i < 4; ++i)
#pragma unroll
        for (int r = 0; r < 4; ++r) {
          const int rl = wm * 64 + kb * 4 + i * 16 + r;
          red[rl * 8 + wn * 2 + 0] = s_[i][r];
          red[rl * 8 + wn * 2 + 1] = ss_[i][r];
        }
    }
    __syncthreads();
#pragma unroll
    for (int i = 0; i < 4; ++i)
#pragma unroll
      for (int r = 0; r < 4; ++r) {
        const int rl = wm * 64 + kb * 4 + i * 16 + r;
        float S = 0.f, SS = 0.f;
#pragma unroll
        for (int q = 0; q < 4; ++q) { S += red[rl * 8 + q * 2]; SS += red[rl * 8 + q * 2 + 1]; }
        const float mean = S * (1.f / D);
        s_[i][r] = mean;
        ss_[i][r] = rsqrtf(SS * (1.f / D) - mean * mean + EPS);
      }
#pragma unroll
    for (int j = 0; j < 4; ++j) {
      const int col = ccol0 + j * 16;
      const float gc = g1[col], bc = b1[col];
#pragma unroll
      for (int i = 0; i < 4; ++i) {
#pragma unroll
        for (int r = 0; r < 4; ++r) {
          const int row = crow0 + i * 16 + r;
          const float xv = (acc[i][j][r] - s_[i][r]) * ss_[i][r] * gc + bc;
          x1[(size_t)row * 256 + col] = f2b(xv);
        }
      }
    }
  }
}

// ------- logits GEMM: C[M,N] f32 = A(bf16) @ W(f32->bf16 reg-staged)^T ------
__global__ __launch_bounds__(256) void bgemm3_k(const unsigned short* __restrict__ A,
                                                const float* __restrict__ Wf,
                                                float* __restrict__ C, int M, int N) {
  __shared__ unsigned short As[128 * 64];
  __shared__ unsigned short Bs[128 * 64];
  const int tid = threadIdx.x, w = tid >> 6, lane = tid & 63;
  const int kb = lane >> 4, ln = lane & 15;
  const int m0 = blockIdx.x * 128;
  const int n0 = blockIdx.y * 128;
  const int wm = w & 1, wn = w >> 1;
  const int rl = lane >> 3;
  const int cb = (lane & 7) << 4;

  f32x4 acc[4][4];
#pragma unroll
  for (int i = 0; i < 4; ++i)
#pragma unroll
    for (int j = 0; j < 4; ++j) acc[i][j] = (f32x4){0.f, 0.f, 0.f, 0.f};

  for (int ks = 0; ks < 4; ++ks) {
    const int ko = ks * 64;
#pragma unroll
    for (int c = 0; c < 4; ++c) {
      const int arow = w * 32 + c * 8 + rl;
      const int sw = (arow & 7) << 4;
      const int cu = (cb ^ sw) >> 1;
      gload_lds16(A + (size_t)(m0 + arow) * 256 + ko + cu, As + (w * 32 + c * 8) * 64);
    }
    // B: reg-stage f32 -> bf16 into swizzled LDS slots
#pragma unroll
    for (int c = 0; c < 4; ++c) {
      const int g = c * 256 + tid;
      const int row = g >> 3, gcs = g & 7;
      int br = n0 + row; if (br > N - 1) br = N - 1;
      const float* src = Wf + (size_t)br * 256 + ko + gcs * 8;
      const float4 f0 = *(const float4*)src;
      const float4 f1 = *(const float4*)(src + 4);
      *(bf16x8*)(Bs + row * 64 + ((gcs ^ (row & 7)) << 3)) = pack8(f0, f1);
    }
    __syncthreads();
#pragma unroll
    for (int h = 0; h < 2; ++h) {
      bf16x8 af[4], bfr[4];
#pragma unroll
      for (int i = 0; i < 4; ++i) {
        const int ar = wm * 64 + i * 16 + ln;
        af[i] = *(const bf16x8*)(As + ar * 64 + (((h * 64 + kb * 16) ^ ((ar & 7) << 4)) >> 1));
        const int br = wn * 64 + i * 16 + ln;
        bfr[i] = *(const bf16x8*)(Bs + br * 64 + (((h * 64 + kb * 16) ^ ((br & 7) << 4)) >> 1));
      }
#pragma unroll
      for (int i = 0; i < 4; ++i)
#pragma unroll
        for (int j = 0; j < 4; ++j)
          acc[i][j] = __builtin_amdgcn_mfma_f32_16x16x32_bf16(af[i], bfr[j], acc[i][j], 0, 0, 0);
    }
    __syncthreads();
  }

  const int crow0 = m0 + wm * 64 + kb * 4;
  const int ccol0 = n0 + wn * 64 + ln;
#pragma unroll
  for (int j = 0; j < 4; ++j) {
    const int col = ccol0 + j * 16;
    if (col >= N) continue;
#pragma unroll
    for (int i = 0; i < 4; ++i) {
#pragma unroll
      for (int r = 0; r < 4; ++r) {
        const int row = crow0 + i * 16 + r;
        C[(size_t)row * N + col] = acc[i][j][r];
      }
    }
  }
}

// ---------------- MFMA causal attention (r6 structure): fragment-major LDS -
// All MFMA operand reads lane-ordered 16B granules (conflict-free). Q is
// pre-scaled by SCALE in the Q-GEMM. O written bf16. LDS 79,872 -> 2 blk/CU.
__global__ __launch_bounds__(256) void attn_k(const unsigned short* __restrict__ Q,
                                              const unsigned short* __restrict__ Kg,
                                              const unsigned short* __restrict__ Vg,
                                              unsigned short* __restrict__ O) {
  __shared__ unsigned short Ks[13312];      // [t*2+h][lane] granules of 8
  __shared__ unsigned short Vt[13312];      // frag-major V^T + 192..207 half tiles
  __shared__ unsigned short Ps[4 * 3328];   // per-wave P, 208 keys
  const int b = blockIdx.x >> 2;
  const int h = blockIdx.x & 3;
  const int tid = threadIdx.x, w = tid >> 6, lane = tid & 63;
  const int kb = lane >> 4, ln = lane & 15;
  const size_t base = (size_t)b * S * D + h * DH;

  for (int s = w; s < 26; s += 4) {
    const int t = s >> 1, h2 = s & 1;
    int krow = t * 16 + ln; if (krow > S - 1) krow = S - 1;
    gload_lds16(Kg + base + (size_t)krow * D + h2 * 32 + kb * 8, Ks + s * 512);
  }
  for (int g = tid; g < 200 * 8; g += 256) {
    const int key = g >> 3, d0 = (g & 7) * 8;
    const bf16x8 v = *(const bf16x8*)(Vg + base + (size_t)key * D + d0);
#pragma unroll
    for (int i = 0; i < 8; ++i) {
      const int d = d0 + i, ct = d >> 4, cl = d & 15;
      int addr;
      if (key < 192) addr = (((ct * 6 + (key >> 5)) * 4 + ((key >> 3) & 3)) * 16 + cl) * 8 + (key & 7);
      else           addr = 12288 + ((ct * 2 + ((key >> 3) & 1)) * 16 + cl) * 8 + (key & 7);
      Vt[addr] = (unsigned short)v[i];
    }
  }
  // zero Vt tail granules for keys 200..207 (never staged)
  if (tid < 64) {
    const int ct = tid >> 4, cl = tid & 15;
    *(bf16x8*)(Vt + 12288 + ((ct * 2 + 1) * 16 + cl) * 8) = (bf16x8)0;
  }
  __syncthreads();
  unsigned short* Pw = Ps + w * 3328;

  for (int q0 = w * 16; q0 < S; q0 += 64) {
    int qr = q0 + ln; if (qr > S - 1) qr = S - 1;
    const unsigned short* qp = Q + base + (size_t)qr * D + kb * 8;
    const bf16x8 aq0 = *(const bf16x8*)(qp);
    const bf16x8 aq1 = *(const bf16x8*)(qp + 32);
    f32x4 sc[13];
#pragma unroll
    for (int t = 0; t < 13; ++t) {
      f32x4 a = {0.f, 0.f, 0.f, 0.f};
      a = __builtin_amdgcn_mfma_f32_16x16x32_bf16(aq0, *(const bf16x8*)(Ks + (t * 2 + 0) * 512 + lane * 8), a, 0, 0, 0);
      a = __builtin_amdgcn_mfma_f32_16x16x32_bf16(aq1, *(const bf16x8*)(Ks + (t * 2 + 1) * 512 + lane * 8), a, 0, 0, 0);
      sc[t] = a;
    }
    float inv[4];
#pragma unroll
    for (int r = 0; r < 4; ++r) {
      const int q = q0 + kb * 4 + r;
      const int qrow = kb * 4 + r;
      float m = -1e30f;
#pragma unroll
      for (int t = 0; t < 13; ++t) {
        const int j = t * 16 + ln;
        float s = sc[t][r];   // Q pre-scaled
        s = (j <= q) ? s : -1e30f;
        sc[t][r] = s;
        m = fmaxf(m, s);
      }
      m = fmaxf(m, __shfl_xor(m, 1));
      m = fmaxf(m, __shfl_xor(m, 2));
      m = fmaxf(m, __shfl_xor(m, 4));
      m = fmaxf(m, __shfl_xor(m, 8));
      float sm = 0.f;
#pragma unroll
      for (int t = 0; t < 13; ++t) {
        const float e = __expf(sc[t][r] - m);
        sm += e;
        int addr;
        if (t < 12) addr = (((t >> 1) * 4 + ((2 * t + (ln >> 3)) & 3)) * 16 + qrow) * 8 + (ln & 7);
        else        addr = 3072 + ((ln >> 3) * 16 + qrow) * 8 + (ln & 7);
        Pw[addr] = f2b(e);
      }
      sm += __shfl_xor(sm, 1);
      sm += __shfl_xor(sm, 2);
      sm += __shfl_xor(sm, 4);
      sm += __shfl_xor(sm, 8);
      inv[r] = 1.f / sm;
    }
#pragma unroll
    for (int ct = 0; ct < 4; ++ct) {
      f32x4 a = {0.f, 0.f, 0.f, 0.f};
#pragma unroll
      for (int kt = 0; kt < 6; ++kt) {
        const bf16x8 pa = *(const bf16x8*)(Pw + ((kt * 4 + kb) * 16 + ln) * 8);
        const bf16x8 vb = *(const bf16x8*)(Vt + (((ct * 6 + kt) * 4 + kb) * 16 + ln) * 8);
        a = __builtin_amdgcn_mfma_f32_16x16x32_bf16(pa, vb, a, 0, 0, 0);
      }
      {
        bf16x8 pa = (bf16x8)0, vb = (bf16x8)0;
        if (kb < 2) {
          pa = *(const bf16x8*)(Pw + 3072 + (kb * 16 + ln) * 8);
          vb = *(const bf16x8*)(Vt + 12288 + ((ct * 2 + kb) * 16 + ln) * 8);
        }
        a = __builtin_amdgcn_mfma_f32_16x16x32_bf16(pa, vb, a, 0, 0, 0);
      }
#pragma unroll
      for (int r = 0; r < 4; ++r) {
        const int q = q0 + kb * 4 + r;
        if (q < S) O[base + (size_t)q * D + ct * 16 + ln] = f2b(a[r] * inv[r]);
      }
    }
  }
}

// ---------------------------------------------------------------------------
extern "C" void kernel_launch(void* const* d_in, const int* in_sizes, int n_in,
                              void* d_out, int out_size, void* d_ws, size_t ws_size,
                              hipStream_t stream) {
  const int* ids        = (const int*)d_in[0];
  const float* item_emb = (const float*)d_in[1];
  const float* pos_emb  = (const float*)d_in[2];
  const float* ln1_g    = (const float*)d_in[3];
  const float* ln1_b    = (const float*)d_in[4];
  const float* wq       = (const float*)d_in[5];
  const float* bq       = (const float*)d_in[6];
  const float* wk       = (const float*)d_in[7];
  const float* bk       = (const float*)d_in[8];
  const float* wv       = (const float*)d_in[9];
  const float* bv       = (const float*)d_in[10];
  const float* ln2_g    = (const float*)d_in[11];
  const float* ln2_b    = (const float*)d_in[12];
  const float* wd       = (const float*)d_in[13];
  const float* bd       = (const float*)d_in[14];
  const float* seq_g    = (const float*)d_in[15];
  const float* seq_b    = (const float*)d_in[16];
  const float* w_out    = (const float*)d_in[17];
  float* out = (float*)d_out;

  // ---- workspace layout (bytes), end = 368,312,320 ----
  char* wsb = (char*)d_ws;
  unsigned short* seq_bf = (unsigned short*)(wsb + 0);
  unsigned short* x_bf   = (unsigned short*)(wsb + 52428800);
  unsigned short* q_bf   = (unsigned short*)(wsb + 104857600);  // q, then t
  unsigned short* k_bf   = (unsigned short*)(wsb + 157286400);
  unsigned short* v_bf   = (unsigned short*)(wsb + 209715200);
  unsigned short* o_bf   = (unsigned short*)(wsb + 262144000);
  unsigned short* x2b    = (unsigned short*)(wsb + 314572800);
  unsigned short* wtb    = (unsigned short*)(wsb + 367001600);  // 1,048,576 B
  unsigned short* semb   = (unsigned short*)(wsb + 368050176);  // 262,144 B

  const int M = B * S;  // 102400
  const int ln_grid = (M + 3) / 4;

  cvt_wt_k<<<512, 256, 0, stream>>>(wq, wk, wv, wd, wtb);
  embed_ln_k<<<ln_grid, 256, 0, stream>>>(ids, item_emb, pos_emb, ln1_g, ln1_b, seq_bf, x_bf);

  for (int blk = 0; blk < 2; ++blk) {
    const float* l2g = ln2_g + blk * D;
    const float* l2b = ln2_b + blk * D;
    const unsigned short* WT = wtb + (size_t)blk * 4 * 65536;  // order: q,k,v,d

    bgemm2_k<0, 0, 0><<<800, 512, 0, stream>>>(seq_bf, WT + 1 * 65536, bk + blk * D, k_bf,
                                               nullptr, nullptr, 1.f, nullptr, nullptr, nullptr);
    bgemm2_k<0, 0, 0><<<800, 512, 0, stream>>>(seq_bf, WT + 2 * 65536, bv + blk * D, v_bf,
                                               nullptr, nullptr, 1.f, nullptr, nullptr, nullptr);
    bgemm2_k<0, 0, 0><<<800, 512, 0, stream>>>(x_bf, WT + 0 * 65536, bq + blk * D, q_bf,
                                               nullptr, nullptr, SCALE, nullptr, nullptr, nullptr);
    attn_k<<<B * H, 256, 0, stream>>>(q_bf, k_bf, v_bf, o_bf);
    ln2x2_k<<<ln_grid, 256, 0, stream>>>(x_bf, o_bf, l2g, l2b, x2b, q_bf, M);
    if (blk == 0) {
      bgemm2_k<1, 1, 1><<<800, 512, 0, stream>>>(q_bf, WT + 3 * 65536, bd + blk * D, seq_bf,
                                                 x2b, ids, 1.f, ln1_g + D, ln1_b + D, x_bf);
    } else {
      bgemm2_k<1, 1, 0><<<800, 512, 0, stream>>>(q_bf, WT + 3 * 65536, bd + blk * D, seq_bf,
                                                 x2b, ids, 1.f, nullptr, nullptr, nullptr);
    }
  }

  ln_bf_k<<<(B + 3) / 4, 256, 0, stream>>>(seq_bf + (size_t)(S - 1) * D, (size_t)S * D,
                                           seq_g, seq_b, semb, B);
  bgemm3_k<<<dim3(4, 782), 256, 0, stream>>>(semb, w_out, out, B, NI);
}